// Round 7
// baseline (6472.459 us; speedup 1.0000x reference)
//
#include <hip/hip_runtime.h>
#include <math.h>

#define T_STEPS 2048
#define HID     128
#define G4      512   // 4*H

typedef _Float16 half8 __attribute__((ext_vector_type(8)));
typedef float    f32x4 __attribute__((ext_vector_type(4)));

__device__ __forceinline__ float fast_sig(float x) {
    return __fdividef(1.0f, 1.0f + __expf(-x));
}
__device__ __forceinline__ float fast_tanh(float x) {
    return fmaf(2.0f, __fdividef(1.0f, 1.0f + __expf(-2.0f * x)), -1.0f);
}
__device__ __forceinline__ f32x4 ld4(const float* p) {
    float4 v = *reinterpret_cast<const float4*>(p);
    f32x4 r; r[0] = v.x; r[1] = v.y; r[2] = v.z; r[3] = v.w; return r;
}
// volatile LDS load: cannot be LICM-hoisted or rematerialized (round-6 lesson)
__device__ __forceinline__ half8 lds_ld(const half8* p) {
    return *(const volatile half8*)p;
}

// ---------------------------------------------------------------------------
// MFMA LSTM recurrence, single live batch element (b = 127).
//
// ROUNDS 2-5: every attempt to keep the weight fragments register-resident
// was defeated by the RA (spill to scratch, FETCH == frag bytes x 2048).
// ROUND 6: weights staged to LDS -- but the per-step ds_reads are loop-
// invariant, so LICM hoisted them back into registers and the RA spilled
// those: FETCH unchanged at 266 MB. THIS ROUND: the per-step LDS reads are
// volatile -> un-hoistable -> the stream-from-LDS schedule is forced.
//
// Weights in LDS as f16 in MFMA-fragment order: slot((wave,r,kt,lane)) =
// ((wave*4+r)*4+kt)*64+lane, 16 B/slot; per-step read is one ds_read_b128
// per (r,kt), 64 lanes contiguous -> conflict-free. Roofline: 131 KB/step
// at 256 B/cyc = ~512 cyc/step.
//
// 512 threads / 8 waves; wave owns 64 gates = 4 row-tiles x 4 k-tiles.
// h broadcast via LDS as f16: ALL 16 B-columns identical -> every C column
// computes the same dot (B n-mapping irrelevant; k-permutation cancels).
// acc[r][reg] = gate jb0 + 16r + 4quad + reg. Lanes col<4 activate row-tile
// r=col&3. Pre-activation added AFTER the MFMA (additive constant).
// ---------------------------------------------------------------------------
template<bool IS_L0>
__global__ __launch_bounds__(512)
void lstm_rec_mfma(const float* __restrict__ Whh,   // (512,128) row-major
                   const float* __restrict__ xin,   // L0: x (T,128) ; L1: G (T,512)
                   const float* __restrict__ wih0,  // L0 only (512,)
                   const float* __restrict__ bih,   // L0 only
                   const float* __restrict__ bhh,   // L0 only
                   float* __restrict__ hout)        // (T,128)
{
    const int tid  = threadIdx.x;
    const int wave = tid >> 6;         // 0..7
    const int lane = tid & 63;
    const int quad = lane >> 4;
    const int col  = lane & 15;
    const int jb0  = wave * 64;        // first gate of this wave
    const int rm   = col & 3;          // row-tile this lane activates
    const int jm   = jb0 + rm * 16 + quad * 4;  // first of 4 gates this lane activates
    const bool act_lane = (col < 4);

    __shared__ __align__(16) _Float16 h16[HID];
    __shared__ __align__(16) float    gact[G4];
    __shared__ __align__(16) half8    wlds[8 * 4 * 4 * 64];   // 131072 B

    // ---- stage Whh into LDS in fragment order (one-time, ~131 KB read) ----
    #pragma unroll
    for (int r = 0; r < 4; ++r) {
        const float* row = Whh + (size_t)(jb0 + r * 16 + col) * HID;
        #pragma unroll
        for (int kt = 0; kt < 4; ++kt) {
            const float4* p = reinterpret_cast<const float4*>(row + kt * 32 + quad * 8);
            float4 lo = p[0], hi = p[1];
            half8 h;
            h[0] = (_Float16)lo.x; h[1] = (_Float16)lo.y;
            h[2] = (_Float16)lo.z; h[3] = (_Float16)lo.w;
            h[4] = (_Float16)hi.x; h[5] = (_Float16)hi.y;
            h[6] = (_Float16)hi.z; h[7] = (_Float16)hi.w;
            wlds[((wave * 4 + r) * 4 + kt) * 64 + lane] = h;
        }
    }

    // L0 constants for THIS lane's activation slice only (8 regs, cheap)
    f32x4 bsel = {0, 0, 0, 0}, wsel = {0, 0, 0, 0};
    if (IS_L0 && act_lane) {
        bsel = ld4(bih + jm) + ld4(bhh + jm);
        wsel = ld4(wih0 + jm);
    }

    float c_reg = 0.0f;
    if (tid < HID) h16[tid] = (_Float16)0.0f;
    __syncthreads();

    // pre-activation pipeline: one float4 per activating lane per step
    f32x4 pre_cur = {0, 0, 0, 0}, pre_nxt = {0, 0, 0, 0};
    if (act_lane) {
        if (IS_L0) pre_cur = bsel + wsel * xin[HID - 1];
        else       pre_cur = ld4(xin + jm);
    }

    const bool is_tanh_wave = ((wave >> 1) == 2);   // gates 256..383 = cell input
    const half8* wbase = &wlds[(wave * 16) * 64 + lane];   // imm offsets cover (r,kt)

    for (int t = 0; t < T_STEPS; ++t) {
        // B fragments: every lane reads the same 8 f16 per k-tile (broadcast)
        half8 bfrag[4];
        #pragma unroll
        for (int kt = 0; kt < 4; ++kt)
            bfrag[kt] = *reinterpret_cast<const half8*>(&h16[kt * 32 + quad * 8]);

        // prefetch next step's pre-activation (hide L2 latency behind MFMA)
        const int tn = (t + 1 < T_STEPS) ? t + 1 : t;
        if (act_lane) {
            if (IS_L0) pre_nxt = bsel + wsel * xin[(size_t)tn * HID + HID - 1];
            else       pre_nxt = ld4(xin + (size_t)tn * G4 + jm);
        }

        // D = Whh_tile @ h : A-frags streamed from LDS via VOLATILE
        // ds_read_b128 (un-hoistable), 16 MFMA, 4 independent acc chains
        f32x4 acc[4] = {};
        #pragma unroll
        for (int kt = 0; kt < 4; ++kt) {
            #pragma unroll
            for (int r = 0; r < 4; ++r) {
                half8 a = lds_ld(wbase + (r * 4 + kt) * 64);
                acc[r] = __builtin_amdgcn_mfma_f32_16x16x32_f16(
                             a, bfrag[kt], acc[r], 0, 0, 0);
            }
        }

        // activation on this lane's slice: unrolled select (no dynamic reg index)
        f32x4 g = {0, 0, 0, 0};
        #pragma unroll
        for (int r = 0; r < 4; ++r)
            if (rm == r) g = acc[r] + pre_cur;
        f32x4 a4;
        if (is_tanh_wave) {
            a4[0] = fast_tanh(g[0]); a4[1] = fast_tanh(g[1]);
            a4[2] = fast_tanh(g[2]); a4[3] = fast_tanh(g[3]);
        } else {
            a4[0] = fast_sig(g[0]); a4[1] = fast_sig(g[1]);
            a4[2] = fast_sig(g[2]); a4[3] = fast_sig(g[3]);
        }
        if (act_lane)
            *reinterpret_cast<f32x4*>(&gact[jm]) = a4;
        __syncthreads();

        // serial tail: c/h update on 128 threads (waves 0-1)
        if (tid < HID) {
            float ai = gact[tid];
            float af = gact[tid + 128];
            float ag = gact[tid + 256];
            float ao = gact[tid + 384];
            c_reg = fmaf(af, c_reg, ai * ag);
            float h = ao * fast_tanh(c_reg);
            hout[(size_t)t * HID + tid] = h;
            h16[tid] = (_Float16)h;
        }
        pre_cur = pre_nxt;
        __syncthreads();
    }
}

// ---------------------------------------------------------------------------
// C[m,n] = sum_k A[m,k] * W[n,k] + b1[n] (+ b2[n])    K = 128 fixed
// ---------------------------------------------------------------------------
#define BM 64
#define BN 64
__global__ __launch_bounds__(256)
void gemm_bias_kernel(const float* __restrict__ A,   // (M,128)
                      const float* __restrict__ W,   // (N,128)
                      const float* __restrict__ b1,
                      const float* __restrict__ b2,  // may be null
                      float* __restrict__ C,         // (M,N)
                      int M, int N)
{
    __shared__ float Al[128][BM + 4];
    __shared__ float Wl[128][BN + 4];
    const int tid    = threadIdx.x;
    const int m_base = blockIdx.x * BM;
    const int n_base = blockIdx.y * BN;

    {
        const int r  = tid >> 2;          // 0..63
        const int kq = (tid & 3) * 32;    // 0,32,64,96
        const float4* srcA = reinterpret_cast<const float4*>(A + (size_t)(m_base + r) * 128 + kq);
        #pragma unroll
        for (int i = 0; i < 8; ++i) {
            float4 v = srcA[i];
            int k = kq + 4 * i;
            Al[k + 0][r] = v.x; Al[k + 1][r] = v.y; Al[k + 2][r] = v.z; Al[k + 3][r] = v.w;
        }
        const float4* srcW = reinterpret_cast<const float4*>(W + (size_t)(n_base + r) * 128 + kq);
        #pragma unroll
        for (int i = 0; i < 8; ++i) {
            float4 v = srcW[i];
            int k = kq + 4 * i;
            Wl[k + 0][r] = v.x; Wl[k + 1][r] = v.y; Wl[k + 2][r] = v.z; Wl[k + 3][r] = v.w;
        }
    }
    __syncthreads();

    const int tm = (tid & 15) * 4;
    const int tn = (tid >> 4) * 4;
    float acc[4][4] = {};
    #pragma unroll 8
    for (int k = 0; k < 128; ++k) {
        float4 av = *reinterpret_cast<const float4*>(&Al[k][tm]);
        float4 wv = *reinterpret_cast<const float4*>(&Wl[k][tn]);
        acc[0][0] = fmaf(av.x, wv.x, acc[0][0]);
        acc[0][1] = fmaf(av.x, wv.y, acc[0][1]);
        acc[0][2] = fmaf(av.x, wv.z, acc[0][2]);
        acc[0][3] = fmaf(av.x, wv.w, acc[0][3]);
        acc[1][0] = fmaf(av.y, wv.x, acc[1][0]);
        acc[1][1] = fmaf(av.y, wv.y, acc[1][1]);
        acc[1][2] = fmaf(av.y, wv.z, acc[1][2]);
        acc[1][3] = fmaf(av.y, wv.w, acc[1][3]);
        acc[2][0] = fmaf(av.z, wv.x, acc[2][0]);
        acc[2][1] = fmaf(av.z, wv.y, acc[2][1]);
        acc[2][2] = fmaf(av.z, wv.z, acc[2][2]);
        acc[2][3] = fmaf(av.z, wv.w, acc[2][3]);
        acc[3][0] = fmaf(av.w, wv.x, acc[3][0]);
        acc[3][1] = fmaf(av.w, wv.y, acc[3][1]);
        acc[3][2] = fmaf(av.w, wv.z, acc[3][2]);
        acc[3][3] = fmaf(av.w, wv.w, acc[3][3]);
    }

    float bias[4];
    #pragma unroll
    for (int i = 0; i < 4; ++i) {
        int n = n_base + tn + i;
        bias[i] = b1[n] + (b2 ? b2[n] : 0.0f);
    }
    #pragma unroll
    for (int mi = 0; mi < 4; ++mi) {
        float4 o;
        o.x = acc[mi][0] + bias[0];
        o.y = acc[mi][1] + bias[1];
        o.z = acc[mi][2] + bias[2];
        o.w = acc[mi][3] + bias[3];
        *reinterpret_cast<float4*>(C + (size_t)(m_base + tm + mi) * N + n_base + tn) = o;
    }
}

// ---------------------------------------------------------------------------
__global__ __launch_bounds__(512)
void bn_stats_kernel(const float* __restrict__ Z,       // (T,128)
                     const float* __restrict__ gamma,
                     const float* __restrict__ beta,
                     float* __restrict__ scale,
                     float* __restrict__ shift)
{
    const int tid = threadIdx.x;
    const int col = tid & 127;
    const int seg = tid >> 7;     // 0..3
    float s = 0.f, sq = 0.f;
    for (int t = seg * 512; t < (seg + 1) * 512; ++t) {
        float v = Z[(size_t)t * 128 + col];
        s += v;
        sq = fmaf(v, v, sq);
    }
    __shared__ float ps[4][128], pq[4][128];
    ps[seg][col] = s;
    pq[seg][col] = sq;
    __syncthreads();
    if (tid < 128) {
        float sum = ps[0][tid] + ps[1][tid] + ps[2][tid] + ps[3][tid];
        float sqq = pq[0][tid] + pq[1][tid] + pq[2][tid] + pq[3][tid];
        float mean = sum * (1.0f / 2048.0f);
        float var  = sqq * (1.0f / 2048.0f) - mean * mean;
        float sc = gamma[tid] * rsqrtf(var + 1e-5f);
        scale[tid] = sc;
        shift[tid] = beta[tid] - mean * sc;
    }
}

// ---------------------------------------------------------------------------
__global__ __launch_bounds__(512)
void fc2_kernel(const float* __restrict__ Z,      // (T,128)
                const float* __restrict__ scale,
                const float* __restrict__ shift,
                const float* __restrict__ fc2_w,  // (8,128)
                const float* __restrict__ fc2_b,
                float* __restrict__ out)          // (T,8)
{
    const int gid = blockIdx.x * blockDim.x + threadIdx.x;   // 0..16383
    const int o = gid & 7;
    const int t = gid >> 3;

    __shared__ float w_s[8][132];
    __shared__ float sc_s[128], sh_s[128];
    for (int i = threadIdx.x; i < 1024; i += 512) w_s[i >> 7][i & 127] = fc2_w[i];
    if (threadIdx.x < 128) {
        sc_s[threadIdx.x] = scale[threadIdx.x];
        sh_s[threadIdx.x] = shift[threadIdx.x];
    }
    __syncthreads();

    float acc = fc2_b[o];
    const float* zrow = Z + (size_t)t * 128;
    #pragma unroll 4
    for (int k = 0; k < 128; ++k) {
        float zn = fmaf(zrow[k], sc_s[k], sh_s[k]);
        zn = fmaxf(zn, 0.0f);
        acc = fmaf(zn, w_s[o][k], acc);
    }
    out[gid] = acc;
}

// ---------------------------------------------------------------------------
extern "C" void kernel_launch(void* const* d_in, const int* in_sizes, int n_in,
                              void* d_out, int out_size, void* d_ws, size_t ws_size,
                              hipStream_t stream)
{
    const float* x     = (const float*)d_in[0];   // (2048,128,1)
    const float* Wih0  = (const float*)d_in[1];   // (512,1)
    const float* Whh0  = (const float*)d_in[2];   // (512,128)
    const float* bih0  = (const float*)d_in[3];
    const float* bhh0  = (const float*)d_in[4];
    const float* Wih1  = (const float*)d_in[5];   // (512,128)
    const float* Whh1  = (const float*)d_in[6];   // (512,128)
    const float* bih1  = (const float*)d_in[7];
    const float* bhh1  = (const float*)d_in[8];
    const float* fc1_w = (const float*)d_in[9];   // (128,128)
    const float* fc1_b = (const float*)d_in[10];
    const float* gamma = (const float*)d_in[11];
    const float* beta  = (const float*)d_in[12];
    const float* fc2_w = (const float*)d_in[13];  // (8,128)
    const float* fc2_b = (const float*)d_in[14];
    float* out = (float*)d_out;                    // (2048,8) fp32

    float* h1    = (float*)d_ws;            // 2048*128
    float* G     = h1  + T_STEPS * HID;     // 2048*512
    float* h2    = G   + T_STEPS * G4;      // 2048*128
    float* z     = h2  + T_STEPS * HID;     // 2048*128
    float* scale = z   + T_STEPS * HID;     // 128
    float* shift = scale + 128;             // 128

    // K1: layer-0 recurrence (only batch element 127 matters)
    lstm_rec_mfma<true><<<1, 512, 0, stream>>>(Whh0, x, Wih0, bih0, bhh0, h1);

    // K2: layer-1 input GEMM: G[t,:] = h1[t,:] @ Wih1^T + (bih1+bhh1)
    dim3 g2(T_STEPS / BM, G4 / BN);
    gemm_bias_kernel<<<g2, 256, 0, stream>>>(h1, Wih1, bih1, bhh1, G, T_STEPS, G4);

    // K3: layer-1 recurrence consuming precomputed G
    lstm_rec_mfma<false><<<1, 512, 0, stream>>>(Whh1, G, nullptr, nullptr, nullptr, h2);

    // K4a: z = h2 @ fc1^T + fc1_b
    dim3 g4(T_STEPS / BM, HID / BN);
    gemm_bias_kernel<<<g4, 256, 0, stream>>>(h2, fc1_w, fc1_b, nullptr, z, T_STEPS, HID);

    // K4b: batchnorm stats over T axis
    bn_stats_kernel<<<1, 512, 0, stream>>>(z, gamma, beta, scale, shift);

    // K4c: normalize + relu + fc2
    fc2_kernel<<<T_STEPS * 8 / 512, 512, 0, stream>>>(z, scale, shift, fc2_w, fc2_b, out);
}

// Round 8
// 4391.617 us; speedup vs baseline: 1.4738x; 1.4738x over previous
//
#include <hip/hip_runtime.h>
#include <math.h>

#define T_STEPS 2048
#define HID     128
#define G4      512   // 4*H

typedef _Float16 half8 __attribute__((ext_vector_type(8)));
typedef float    f32x4 __attribute__((ext_vector_type(4)));
typedef __attribute__((address_space(3))) const half8 lds_half8_t;

__device__ __forceinline__ float fast_sig(float x) {
    return __fdividef(1.0f, 1.0f + __expf(-x));
}
__device__ __forceinline__ float fast_tanh(float x) {
    return fmaf(2.0f, __fdividef(1.0f, 1.0f + __expf(-2.0f * x)), -1.0f);
}
__device__ __forceinline__ f32x4 ld4(const float* p) {
    float4 v = *reinterpret_cast<const float4*>(p);
    f32x4 r; r[0] = v.x; r[1] = v.y; r[2] = v.z; r[3] = v.w; return r;
}

// ---------------------------------------------------------------------------
// MFMA LSTM recurrence, single live batch element (b = 127).
//
// Rounds 1-7 established: per-step operand traffic was stuck at 131 KB/step
// sourced from scratch/L2 (~60 B/cyc/CU -> ~2200+ cyc/step) no matter how
// the weights were held. Register residency is unwinnable (RA spills under
// its occupancy heuristic: r2-r5). LDS residency failed twice on codegen:
// r6 -- plain ds_reads of loop-invariant addresses were LICM-hoisted back
// into registers and spilled; r7 -- volatile reads became strictly-ordered
// per-load-waited accesses (+1000 cyc/step) and didn't fix the traffic.
//
// THIS ROUND: weight reads go through a 32-bit LDS byte offset that an empty
// `asm volatile` redefines EVERY t-iteration, cast to an address_space(3)
// pointer. The loads are then (a) un-hoistable -- the address is opaque and
// iteration-fresh, so there is no loop-invariant value to spill -- and
// (b) ordinary ds_read_b128 that the scheduler pipelines against MFMA.
//
// Layout: weights in LDS as f16 in MFMA-fragment order, slot((wave,r,kt,
// lane)) = ((wave*4+r)*4+kt)*64+lane, 16 B/slot. Per-step read = one
// ds_read_b128 per (r,kt) with 64 lanes contiguous (conflict-free), imm
// offsets (r*4+kt)*1024 B. Roofline: 131 KB/step at 256 B/cyc = 512 cyc.
//
// 512 threads / 8 waves; wave owns 64 gates = 4 row-tiles x 4 k-tiles.
// h broadcast via LDS as f16: ALL 16 B-columns identical -> every C column
// computes the same dot (B n-mapping irrelevant; k-permutation cancels).
// acc[r][reg] = gate jb0 + 16r + 4quad + reg. Lanes col<4 activate row-tile
// r=col&3. Pre-activation added AFTER the MFMA (additive constant).
// ---------------------------------------------------------------------------
template<bool IS_L0>
__global__ __launch_bounds__(512)
void lstm_rec_mfma(const float* __restrict__ Whh,   // (512,128) row-major
                   const float* __restrict__ xin,   // L0: x (T,128) ; L1: G (T,512)
                   const float* __restrict__ wih0,  // L0 only (512,)
                   const float* __restrict__ bih,   // L0 only
                   const float* __restrict__ bhh,   // L0 only
                   float* __restrict__ hout)        // (T,128)
{
    const int tid  = threadIdx.x;
    const int wave = tid >> 6;         // 0..7
    const int lane = tid & 63;
    const int quad = lane >> 4;
    const int col  = lane & 15;
    const int jb0  = wave * 64;        // first gate of this wave
    const int rm   = col & 3;          // row-tile this lane activates
    const int jm   = jb0 + rm * 16 + quad * 4;  // first of 4 gates this lane activates
    const bool act_lane = (col < 4);

    __shared__ __align__(16) _Float16 h16[HID];
    __shared__ __align__(16) float    gact[G4];
    __shared__ __align__(16) half8    wlds[8 * 4 * 4 * 64];   // 131072 B

    // ---- stage Whh into LDS in fragment order (one-time, ~256 KB read) ----
    #pragma unroll
    for (int r = 0; r < 4; ++r) {
        const float* row = Whh + (size_t)(jb0 + r * 16 + col) * HID;
        #pragma unroll
        for (int kt = 0; kt < 4; ++kt) {
            const float4* p = reinterpret_cast<const float4*>(row + kt * 32 + quad * 8);
            float4 lo = p[0], hi = p[1];
            half8 h;
            h[0] = (_Float16)lo.x; h[1] = (_Float16)lo.y;
            h[2] = (_Float16)lo.z; h[3] = (_Float16)lo.w;
            h[4] = (_Float16)hi.x; h[5] = (_Float16)hi.y;
            h[6] = (_Float16)hi.z; h[7] = (_Float16)hi.w;
            wlds[((wave * 4 + r) * 4 + kt) * 64 + lane] = h;
        }
    }

    // 32-bit LDS byte offset of this (wave,lane)'s fragment base
    const unsigned wbyte =
        (unsigned)(size_t)(lds_half8_t*)&wlds[(wave * 16) * 64 + lane];

    // L0 constants for THIS lane's activation slice only (8 regs, cheap)
    f32x4 bsel = {0, 0, 0, 0}, wsel = {0, 0, 0, 0};
    if (IS_L0 && act_lane) {
        bsel = ld4(bih + jm) + ld4(bhh + jm);
        wsel = ld4(wih0 + jm);
    }

    float c_reg = 0.0f;
    if (tid < HID) h16[tid] = (_Float16)0.0f;
    __syncthreads();

    // pre-activation pipeline: one float4 per activating lane per step
    f32x4 pre_cur = {0, 0, 0, 0}, pre_nxt = {0, 0, 0, 0};
    if (act_lane) {
        if (IS_L0) pre_cur = bsel + wsel * xin[HID - 1];
        else       pre_cur = ld4(xin + jm);
    }

    const bool is_tanh_wave = ((wave >> 1) == 2);   // gates 256..383 = cell input

    for (int t = 0; t < T_STEPS; ++t) {
        // opaque, iteration-fresh LDS base: defeats LICM without volatile
        unsigned wot = wbyte;
        asm volatile("" : "+v"(wot));
        lds_half8_t* wp = (lds_half8_t*)(size_t)wot;

        // B fragments: every lane reads the same 8 f16 per k-tile (broadcast)
        half8 bfrag[4];
        #pragma unroll
        for (int kt = 0; kt < 4; ++kt)
            bfrag[kt] = *reinterpret_cast<const half8*>(&h16[kt * 32 + quad * 8]);

        // prefetch next step's pre-activation (hide L2 latency behind MFMA)
        const int tn = (t + 1 < T_STEPS) ? t + 1 : t;
        if (act_lane) {
            if (IS_L0) pre_nxt = bsel + wsel * xin[(size_t)tn * HID + HID - 1];
            else       pre_nxt = ld4(xin + (size_t)tn * G4 + jm);
        }

        // D = Whh_tile @ h : A-frags streamed from LDS (ds_read_b128, imm
        // offsets, conflict-free), 16 MFMA, 4 independent acc chains
        f32x4 acc[4] = {};
        #pragma unroll
        for (int kt = 0; kt < 4; ++kt) {
            #pragma unroll
            for (int r = 0; r < 4; ++r) {
                half8 a = wp[(r * 4 + kt) * 64];
                acc[r] = __builtin_amdgcn_mfma_f32_16x16x32_f16(
                             a, bfrag[kt], acc[r], 0, 0, 0);
            }
        }

        // activation on this lane's slice: unrolled select (no dynamic reg index)
        f32x4 g = {0, 0, 0, 0};
        #pragma unroll
        for (int r = 0; r < 4; ++r)
            if (rm == r) g = acc[r] + pre_cur;
        f32x4 a4;
        if (is_tanh_wave) {
            a4[0] = fast_tanh(g[0]); a4[1] = fast_tanh(g[1]);
            a4[2] = fast_tanh(g[2]); a4[3] = fast_tanh(g[3]);
        } else {
            a4[0] = fast_sig(g[0]); a4[1] = fast_sig(g[1]);
            a4[2] = fast_sig(g[2]); a4[3] = fast_sig(g[3]);
        }
        if (act_lane)
            *reinterpret_cast<f32x4*>(&gact[jm]) = a4;
        __syncthreads();

        // serial tail: c/h update on 128 threads (waves 0-1)
        if (tid < HID) {
            float ai = gact[tid];
            float af = gact[tid + 128];
            float ag = gact[tid + 256];
            float ao = gact[tid + 384];
            c_reg = fmaf(af, c_reg, ai * ag);
            float h = ao * fast_tanh(c_reg);
            hout[(size_t)t * HID + tid] = h;
            h16[tid] = (_Float16)h;
        }
        pre_cur = pre_nxt;
        __syncthreads();
    }
}

// ---------------------------------------------------------------------------
// C[m,n] = sum_k A[m,k] * W[n,k] + b1[n] (+ b2[n])    K = 128 fixed
// ---------------------------------------------------------------------------
#define BM 64
#define BN 64
__global__ __launch_bounds__(256)
void gemm_bias_kernel(const float* __restrict__ A,   // (M,128)
                      const float* __restrict__ W,   // (N,128)
                      const float* __restrict__ b1,
                      const float* __restrict__ b2,  // may be null
                      float* __restrict__ C,         // (M,N)
                      int M, int N)
{
    __shared__ float Al[128][BM + 4];
    __shared__ float Wl[128][BN + 4];
    const int tid    = threadIdx.x;
    const int m_base = blockIdx.x * BM;
    const int n_base = blockIdx.y * BN;

    {
        const int r  = tid >> 2;          // 0..63
        const int kq = (tid & 3) * 32;    // 0,32,64,96
        const float4* srcA = reinterpret_cast<const float4*>(A + (size_t)(m_base + r) * 128 + kq);
        #pragma unroll
        for (int i = 0; i < 8; ++i) {
            float4 v = srcA[i];
            int k = kq + 4 * i;
            Al[k + 0][r] = v.x; Al[k + 1][r] = v.y; Al[k + 2][r] = v.z; Al[k + 3][r] = v.w;
        }
        const float4* srcW = reinterpret_cast<const float4*>(W + (size_t)(n_base + r) * 128 + kq);
        #pragma unroll
        for (int i = 0; i < 8; ++i) {
            float4 v = srcW[i];
            int k = kq + 4 * i;
            Wl[k + 0][r] = v.x; Wl[k + 1][r] = v.y; Wl[k + 2][r] = v.z; Wl[k + 3][r] = v.w;
        }
    }
    __syncthreads();

    const int tm = (tid & 15) * 4;
    const int tn = (tid >> 4) * 4;
    float acc[4][4] = {};
    #pragma unroll 8
    for (int k = 0; k < 128; ++k) {
        float4 av = *reinterpret_cast<const float4*>(&Al[k][tm]);
        float4 wv = *reinterpret_cast<const float4*>(&Wl[k][tn]);
        acc[0][0] = fmaf(av.x, wv.x, acc[0][0]);
        acc[0][1] = fmaf(av.x, wv.y, acc[0][1]);
        acc[0][2] = fmaf(av.x, wv.z, acc[0][2]);
        acc[0][3] = fmaf(av.x, wv.w, acc[0][3]);
        acc[1][0] = fmaf(av.y, wv.x, acc[1][0]);
        acc[1][1] = fmaf(av.y, wv.y, acc[1][1]);
        acc[1][2] = fmaf(av.y, wv.z, acc[1][2]);
        acc[1][3] = fmaf(av.y, wv.w, acc[1][3]);
        acc[2][0] = fmaf(av.z, wv.x, acc[2][0]);
        acc[2][1] = fmaf(av.z, wv.y, acc[2][1]);
        acc[2][2] = fmaf(av.z, wv.z, acc[2][2]);
        acc[2][3] = fmaf(av.z, wv.w, acc[2][3]);
        acc[3][0] = fmaf(av.w, wv.x, acc[3][0]);
        acc[3][1] = fmaf(av.w, wv.y, acc[3][1]);
        acc[3][2] = fmaf(av.w, wv.z, acc[3][2]);
        acc[3][3] = fmaf(av.w, wv.w, acc[3][3]);
    }

    float bias[4];
    #pragma unroll
    for (int i = 0; i < 4; ++i) {
        int n = n_base + tn + i;
        bias[i] = b1[n] + (b2 ? b2[n] : 0.0f);
    }
    #pragma unroll
    for (int mi = 0; mi < 4; ++mi) {
        float4 o;
        o.x = acc[mi][0] + bias[0];
        o.y = acc[mi][1] + bias[1];
        o.z = acc[mi][2] + bias[2];
        o.w = acc[mi][3] + bias[3];
        *reinterpret_cast<float4*>(C + (size_t)(m_base + tm + mi) * N + n_base + tn) = o;
    }
}

// ---------------------------------------------------------------------------
__global__ __launch_bounds__(512)
void bn_stats_kernel(const float* __restrict__ Z,       // (T,128)
                     const float* __restrict__ gamma,
                     const float* __restrict__ beta,
                     float* __restrict__ scale,
                     float* __restrict__ shift)
{
    const int tid = threadIdx.x;
    const int col = tid & 127;
    const int seg = tid >> 7;     // 0..3
    float s = 0.f, sq = 0.f;
    for (int t = seg * 512; t < (seg + 1) * 512; ++t) {
        float v = Z[(size_t)t * 128 + col];
        s += v;
        sq = fmaf(v, v, sq);
    }
    __shared__ float ps[4][128], pq[4][128];
    ps[seg][col] = s;
    pq[seg][col] = sq;
    __syncthreads();
    if (tid < 128) {
        float sum = ps[0][tid] + ps[1][tid] + ps[2][tid] + ps[3][tid];
        float sqq = pq[0][tid] + pq[1][tid] + pq[2][tid] + pq[3][tid];
        float mean = sum * (1.0f / 2048.0f);
        float var  = sqq * (1.0f / 2048.0f) - mean * mean;
        float sc = gamma[tid] * rsqrtf(var + 1e-5f);
        scale[tid] = sc;
        shift[tid] = beta[tid] - mean * sc;
    }
}

// ---------------------------------------------------------------------------
__global__ __launch_bounds__(512)
void fc2_kernel(const float* __restrict__ Z,      // (T,128)
                const float* __restrict__ scale,
                const float* __restrict__ shift,
                const float* __restrict__ fc2_w,  // (8,128)
                const float* __restrict__ fc2_b,
                float* __restrict__ out)          // (T,8)
{
    const int gid = blockIdx.x * blockDim.x + threadIdx.x;   // 0..16383
    const int o = gid & 7;
    const int t = gid >> 3;

    __shared__ float w_s[8][132];
    __shared__ float sc_s[128], sh_s[128];
    for (int i = threadIdx.x; i < 1024; i += 512) w_s[i >> 7][i & 127] = fc2_w[i];
    if (threadIdx.x < 128) {
        sc_s[threadIdx.x] = scale[threadIdx.x];
        sh_s[threadIdx.x] = shift[threadIdx.x];
    }
    __syncthreads();

    float acc = fc2_b[o];
    const float* zrow = Z + (size_t)t * 128;
    #pragma unroll 4
    for (int k = 0; k < 128; ++k) {
        float zn = fmaf(zrow[k], sc_s[k], sh_s[k]);
        zn = fmaxf(zn, 0.0f);
        acc = fmaf(zn, w_s[o][k], acc);
    }
    out[gid] = acc;
}

// ---------------------------------------------------------------------------
extern "C" void kernel_launch(void* const* d_in, const int* in_sizes, int n_in,
                              void* d_out, int out_size, void* d_ws, size_t ws_size,
                              hipStream_t stream)
{
    const float* x     = (const float*)d_in[0];   // (2048,128,1)
    const float* Wih0  = (const float*)d_in[1];   // (512,1)
    const float* Whh0  = (const float*)d_in[2];   // (512,128)
    const float* bih0  = (const float*)d_in[3];
    const float* bhh0  = (const float*)d_in[4];
    const float* Wih1  = (const float*)d_in[5];   // (512,128)
    const float* Whh1  = (const float*)d_in[6];   // (512,128)
    const float* bih1  = (const float*)d_in[7];
    const float* bhh1  = (const float*)d_in[8];
    const float* fc1_w = (const float*)d_in[9];   // (128,128)
    const float* fc1_b = (const float*)d_in[10];
    const float* gamma = (const float*)d_in[11];
    const float* beta  = (const float*)d_in[12];
    const float* fc2_w = (const float*)d_in[13];  // (8,128)
    const float* fc2_b = (const float*)d_in[14];
    float* out = (float*)d_out;                    // (2048,8) fp32

    float* h1    = (float*)d_ws;            // 2048*128
    float* G     = h1  + T_STEPS * HID;     // 2048*512
    float* h2    = G   + T_STEPS * G4;      // 2048*128
    float* z     = h2  + T_STEPS * HID;     // 2048*128
    float* scale = z   + T_STEPS * HID;     // 128
    float* shift = scale + 128;             // 128

    // K1: layer-0 recurrence (only batch element 127 matters)
    lstm_rec_mfma<true><<<1, 512, 0, stream>>>(Whh0, x, Wih0, bih0, bhh0, h1);

    // K2: layer-1 input GEMM: G[t,:] = h1[t,:] @ Wih1^T + (bih1+bhh1)
    dim3 g2(T_STEPS / BM, G4 / BN);
    gemm_bias_kernel<<<g2, 256, 0, stream>>>(h1, Wih1, bih1, bhh1, G, T_STEPS, G4);

    // K3: layer-1 recurrence consuming precomputed G
    lstm_rec_mfma<false><<<1, 512, 0, stream>>>(Whh1, G, nullptr, nullptr, nullptr, h2);

    // K4a: z = h2 @ fc1^T + fc1_b
    dim3 g4(T_STEPS / BM, HID / BN);
    gemm_bias_kernel<<<g4, 256, 0, stream>>>(h2, fc1_w, fc1_b, nullptr, z, T_STEPS, HID);

    // K4b: batchnorm stats over T axis
    bn_stats_kernel<<<1, 512, 0, stream>>>(z, gamma, beta, scale, shift);

    // K4c: normalize + relu + fc2
    fc2_kernel<<<T_STEPS * 8 / 512, 512, 0, stream>>>(z, scale, shift, fc2_w, fc2_b, out);
}

// Round 9
// 3824.026 us; speedup vs baseline: 1.6926x; 1.1484x over previous
//
#include <hip/hip_runtime.h>
#include <math.h>

#define T_STEPS 2048
#define HID     128
#define G4      512   // 4*H

typedef _Float16 half8 __attribute__((ext_vector_type(8)));
typedef float    f32x4 __attribute__((ext_vector_type(4)));
typedef int      i32x4 __attribute__((ext_vector_type(4)));

__device__ __forceinline__ float fast_sig(float x) {
    return __fdividef(1.0f, 1.0f + __expf(-x));
}
__device__ __forceinline__ float fast_tanh(float x) {
    return fmaf(2.0f, __fdividef(1.0f, 1.0f + __expf(-2.0f * x)), -1.0f);
}
__device__ __forceinline__ f32x4 ld4(const float* p) {
    float4 v = *reinterpret_cast<const float4*>(p);
    f32x4 r; r[0] = v.x; r[1] = v.y; r[2] = v.z; r[3] = v.w; return r;
}

union HU { half8 h; i32x4 i; };

// build the f16 A-fragment for (r,kt): A[m = jb0+r*16+col][k = kt*32+quad*8+j]
__device__ __forceinline__ i32x4 make_frag(const float* __restrict__ Whh,
                                           int jb0, int r, int kt,
                                           int col, int quad) {
    const float* p = Whh + (size_t)(jb0 + r * 16 + col) * HID + kt * 32 + quad * 8;
    float4 lo = *reinterpret_cast<const float4*>(p);
    float4 hi = *reinterpret_cast<const float4*>(p + 4);
    HU u;
    u.h[0] = (_Float16)lo.x; u.h[1] = (_Float16)lo.y;
    u.h[2] = (_Float16)lo.z; u.h[3] = (_Float16)lo.w;
    u.h[4] = (_Float16)hi.x; u.h[5] = (_Float16)hi.y;
    u.h[6] = (_Float16)hi.z; u.h[7] = (_Float16)hi.w;
    return u.i;
}

// stage one fragment into hard-named AGPRs aB0..aB3 (RA cannot touch/spill these)
#define PUT(B0,B1,B2,B3,R,KT)                                                  \
    { i32x4 u = make_frag(Whh, jb0, R, KT, col, quad);                         \
      asm volatile("v_accvgpr_write_b32 a" #B0 ", %0\n\t"                      \
                   "v_accvgpr_write_b32 a" #B1 ", %1\n\t"                      \
                   "v_accvgpr_write_b32 a" #B2 ", %2\n\t"                      \
                   "v_accvgpr_write_b32 a" #B3 ", %3"                          \
                   :: "v"(u[0]), "v"(u[1]), "v"(u[2]), "v"(u[3])               \
                   : "a" #B0, "a" #B1, "a" #B2, "a" #B3); }

#define A_CLOBBERS \
    "a0","a1","a2","a3","a4","a5","a6","a7","a8","a9","a10","a11","a12","a13", \
    "a14","a15","a16","a17","a18","a19","a20","a21","a22","a23","a24","a25",   \
    "a26","a27","a28","a29","a30","a31","a32","a33","a34","a35","a36","a37",   \
    "a38","a39","a40","a41","a42","a43","a44","a45","a46","a47","a48","a49",   \
    "a50","a51","a52","a53","a54","a55","a56","a57","a58","a59","a60","a61",   \
    "a62","a63","a64","a65","a66","a67","a68","a69","a70","a71","a72","a73",   \
    "a74","a75","a76","a77","a78","a79","a80","a81","a82","a83"

// ---------------------------------------------------------------------------
// MFMA LSTM recurrence, single live batch element (b = 127).
//
// ERRATA (round 8): FETCH_SIZE is KB, not MB. All rounds fetched the weight
// matrix from HBM exactly ONCE (265 KB); the per-step cost was the weight
// OPERAND FLOW -- RA-spilled scratch reloads served from L2 at ~60 B/cyc/CU
// (131 KB/step = ~2200 cyc, matching r1-r5) or LDS-issue serialization (r8).
// The RA spilled every compiler-managed residency attempt (r2-r5).
//
// THIS ROUND: weights live in PHYSICAL AGPRs a0..a63, written by inline-asm
// v_accvgpr_write with literal register names; accumulators in a64..a79;
// zero-quad in a80..a83. Every asm block lists a0-a83 as clobbers, so the
// compiler can neither allocate nor spill them. The 16 per-step MFMAs read
// A directly from the AGPR file (the native MFMA operand path): per-step
// weight movement is ZERO. B (h) comes from LDS as before; chains are
// interleaved at distance 4 (hazard-safe); 2x s_nop 7 before the
// v_accvgpr_read readouts covers the D-read-after-MFMA wait.
//
// Partition (verified r2-r8): 512 thr / 8 waves; wave owns 64 gates =
// 4 row-tiles x 4 k-tiles. h broadcast via LDS f16, all 16 B-columns
// identical. acc chain r, reg g = gate jb0 + 16r + 4quad + g. Lanes col<4
// activate row-tile rm=col&3; pre-activation added AFTER the MFMA.
// ---------------------------------------------------------------------------
template<bool IS_L0>
__global__ __launch_bounds__(512)
void lstm_rec_mfma(const float* __restrict__ Whh,   // (512,128) row-major
                   const float* __restrict__ xin,   // L0: x (T,128) ; L1: G (T,512)
                   const float* __restrict__ wih0,  // L0 only (512,)
                   const float* __restrict__ bih,   // L0 only
                   const float* __restrict__ bhh,   // L0 only
                   float* __restrict__ hout)        // (T,128)
{
    const int tid  = threadIdx.x;
    const int wave = tid >> 6;         // 0..7
    const int lane = tid & 63;
    const int quad = lane >> 4;
    const int col  = lane & 15;
    const int jb0  = wave * 64;        // first gate of this wave
    const int rm   = col & 3;          // row-tile this lane activates
    const int jm   = jb0 + rm * 16 + quad * 4;  // first of 4 gates this lane activates
    const bool act_lane = (col < 4);

    __shared__ __align__(16) _Float16 h16[HID];
    __shared__ __align__(16) float    gact[G4];

    // ---- stage Whh into AGPRs a0..a63: frag (r,kt) -> a[(r*4+kt)*4 ..+3] ----
    PUT( 0, 1, 2, 3, 0, 0)  PUT( 4, 5, 6, 7, 0, 1)
    PUT( 8, 9,10,11, 0, 2)  PUT(12,13,14,15, 0, 3)
    PUT(16,17,18,19, 1, 0)  PUT(20,21,22,23, 1, 1)
    PUT(24,25,26,27, 1, 2)  PUT(28,29,30,31, 1, 3)
    PUT(32,33,34,35, 2, 0)  PUT(36,37,38,39, 2, 1)
    PUT(40,41,42,43, 2, 2)  PUT(44,45,46,47, 2, 3)
    PUT(48,49,50,51, 3, 0)  PUT(52,53,54,55, 3, 1)
    PUT(56,57,58,59, 3, 2)  PUT(60,61,62,63, 3, 3)
    // zero-quad for the first MFMA of each chain (C input)
    asm volatile("v_accvgpr_write_b32 a80, 0\n\t"
                 "v_accvgpr_write_b32 a81, 0\n\t"
                 "v_accvgpr_write_b32 a82, 0\n\t"
                 "v_accvgpr_write_b32 a83, 0\n\t"
                 "s_nop 7" ::: "a80", "a81", "a82", "a83");

    // L0 constants for THIS lane's activation slice only (8 regs)
    f32x4 bsel = {0, 0, 0, 0}, wsel = {0, 0, 0, 0};
    if (IS_L0 && act_lane) {
        bsel = ld4(bih + jm) + ld4(bhh + jm);
        wsel = ld4(wih0 + jm);
    }

    float c_reg = 0.0f;
    if (tid < HID) h16[tid] = (_Float16)0.0f;
    __syncthreads();

    // pre-activation pipeline: one float4 per activating lane per step
    f32x4 pre_cur = {0, 0, 0, 0}, pre_nxt = {0, 0, 0, 0};
    if (act_lane) {
        if (IS_L0) pre_cur = bsel + wsel * xin[HID - 1];
        else       pre_cur = ld4(xin + jm);
    }

    const bool is_tanh_wave = ((wave >> 1) == 2);   // gates 256..383 = cell input

    for (int t = 0; t < T_STEPS; ++t) {
        // B fragments: every lane reads the same 8 f16 per k-tile (broadcast)
        i32x4 b0, b1, b2, b3;
        { HU u;
          u.h = *reinterpret_cast<const half8*>(&h16[0 * 32 + quad * 8]); b0 = u.i;
          u.h = *reinterpret_cast<const half8*>(&h16[1 * 32 + quad * 8]); b1 = u.i;
          u.h = *reinterpret_cast<const half8*>(&h16[2 * 32 + quad * 8]); b2 = u.i;
          u.h = *reinterpret_cast<const half8*>(&h16[3 * 32 + quad * 8]); b3 = u.i; }

        // prefetch next step's pre-activation (hide latency behind MFMA)
        const int tn = (t + 1 < T_STEPS) ? t + 1 : t;
        if (act_lane) {
            if (IS_L0) pre_nxt = bsel + wsel * xin[(size_t)tn * HID + HID - 1];
            else       pre_nxt = ld4(xin + (size_t)tn * G4 + jm);
        }

        // D = Whh_tile @ h : A from resident AGPRs (zero per-step weight
        // movement). Chains interleaved at distance 4; readout after 2 nops.
        float f0, f1, f2, f3, f4, f5, f6, f7, f8, f9, f10, f11, f12, f13, f14, f15;
        asm volatile(
            "v_mfma_f32_16x16x32_f16 a[64:67], a[0:3],   %16, a[80:83]\n\t"
            "v_mfma_f32_16x16x32_f16 a[68:71], a[16:19], %16, a[80:83]\n\t"
            "v_mfma_f32_16x16x32_f16 a[72:75], a[32:35], %16, a[80:83]\n\t"
            "v_mfma_f32_16x16x32_f16 a[76:79], a[48:51], %16, a[80:83]\n\t"
            "v_mfma_f32_16x16x32_f16 a[64:67], a[4:7],   %17, a[64:67]\n\t"
            "v_mfma_f32_16x16x32_f16 a[68:71], a[20:23], %17, a[68:71]\n\t"
            "v_mfma_f32_16x16x32_f16 a[72:75], a[36:39], %17, a[72:75]\n\t"
            "v_mfma_f32_16x16x32_f16 a[76:79], a[52:55], %17, a[76:79]\n\t"
            "v_mfma_f32_16x16x32_f16 a[64:67], a[8:11],  %18, a[64:67]\n\t"
            "v_mfma_f32_16x16x32_f16 a[68:71], a[24:27], %18, a[68:71]\n\t"
            "v_mfma_f32_16x16x32_f16 a[72:75], a[40:43], %18, a[72:75]\n\t"
            "v_mfma_f32_16x16x32_f16 a[76:79], a[56:59], %18, a[76:79]\n\t"
            "v_mfma_f32_16x16x32_f16 a[64:67], a[12:15], %19, a[64:67]\n\t"
            "v_mfma_f32_16x16x32_f16 a[68:71], a[28:31], %19, a[68:71]\n\t"
            "v_mfma_f32_16x16x32_f16 a[72:75], a[44:47], %19, a[72:75]\n\t"
            "v_mfma_f32_16x16x32_f16 a[76:79], a[60:63], %19, a[76:79]\n\t"
            "s_nop 7\n\t"
            "s_nop 7\n\t"
            "v_accvgpr_read_b32 %0,  a64\n\t"
            "v_accvgpr_read_b32 %1,  a65\n\t"
            "v_accvgpr_read_b32 %2,  a66\n\t"
            "v_accvgpr_read_b32 %3,  a67\n\t"
            "v_accvgpr_read_b32 %4,  a68\n\t"
            "v_accvgpr_read_b32 %5,  a69\n\t"
            "v_accvgpr_read_b32 %6,  a70\n\t"
            "v_accvgpr_read_b32 %7,  a71\n\t"
            "v_accvgpr_read_b32 %8,  a72\n\t"
            "v_accvgpr_read_b32 %9,  a73\n\t"
            "v_accvgpr_read_b32 %10, a74\n\t"
            "v_accvgpr_read_b32 %11, a75\n\t"
            "v_accvgpr_read_b32 %12, a76\n\t"
            "v_accvgpr_read_b32 %13, a77\n\t"
            "v_accvgpr_read_b32 %14, a78\n\t"
            "v_accvgpr_read_b32 %15, a79"
            : "=v"(f0), "=v"(f1), "=v"(f2), "=v"(f3),
              "=v"(f4), "=v"(f5), "=v"(f6), "=v"(f7),
              "=v"(f8), "=v"(f9), "=v"(f10), "=v"(f11),
              "=v"(f12), "=v"(f13), "=v"(f14), "=v"(f15)
            : "v"(b0), "v"(b1), "v"(b2), "v"(b3)
            : A_CLOBBERS);

        // activation on this lane's slice: unrolled chain select
        f32x4 g;
        if      (rm == 0) { g[0] = f0;  g[1] = f1;  g[2] = f2;  g[3] = f3;  }
        else if (rm == 1) { g[0] = f4;  g[1] = f5;  g[2] = f6;  g[3] = f7;  }
        else if (rm == 2) { g[0] = f8;  g[1] = f9;  g[2] = f10; g[3] = f11; }
        else              { g[0] = f12; g[1] = f13; g[2] = f14; g[3] = f15; }
        g += pre_cur;
        f32x4 a4;
        if (is_tanh_wave) {
            a4[0] = fast_tanh(g[0]); a4[1] = fast_tanh(g[1]);
            a4[2] = fast_tanh(g[2]); a4[3] = fast_tanh(g[3]);
        } else {
            a4[0] = fast_sig(g[0]); a4[1] = fast_sig(g[1]);
            a4[2] = fast_sig(g[2]); a4[3] = fast_sig(g[3]);
        }
        if (act_lane)
            *reinterpret_cast<f32x4*>(&gact[jm]) = a4;
        __syncthreads();

        // serial tail: c/h update on 128 threads (waves 0-1)
        if (tid < HID) {
            float ai = gact[tid];
            float af = gact[tid + 128];
            float ag = gact[tid + 256];
            float ao = gact[tid + 384];
            c_reg = fmaf(af, c_reg, ai * ag);
            float h = ao * fast_tanh(c_reg);
            hout[(size_t)t * HID + tid] = h;
            h16[tid] = (_Float16)h;
        }
        pre_cur = pre_nxt;
        __syncthreads();
    }
}

// ---------------------------------------------------------------------------
// C[m,n] = sum_k A[m,k] * W[n,k] + b1[n] (+ b2[n])    K = 128 fixed
// ---------------------------------------------------------------------------
#define BM 64
#define BN 64
__global__ __launch_bounds__(256)
void gemm_bias_kernel(const float* __restrict__ A,   // (M,128)
                      const float* __restrict__ W,   // (N,128)
                      const float* __restrict__ b1,
                      const float* __restrict__ b2,  // may be null
                      float* __restrict__ C,         // (M,N)
                      int M, int N)
{
    __shared__ float Al[128][BM + 4];
    __shared__ float Wl[128][BN + 4];
    const int tid    = threadIdx.x;
    const int m_base = blockIdx.x * BM;
    const int n_base = blockIdx.y * BN;

    {
        const int r  = tid >> 2;          // 0..63
        const int kq = (tid & 3) * 32;    // 0,32,64,96
        const float4* srcA = reinterpret_cast<const float4*>(A + (size_t)(m_base + r) * 128 + kq);
        #pragma unroll
        for (int i = 0; i < 8; ++i) {
            float4 v = srcA[i];
            int k = kq + 4 * i;
            Al[k + 0][r] = v.x; Al[k + 1][r] = v.y; Al[k + 2][r] = v.z; Al[k + 3][r] = v.w;
        }
        const float4* srcW = reinterpret_cast<const float4*>(W + (size_t)(n_base + r) * 128 + kq);
        #pragma unroll
        for (int i = 0; i < 8; ++i) {
            float4 v = srcW[i];
            int k = kq + 4 * i;
            Wl[k + 0][r] = v.x; Wl[k + 1][r] = v.y; Wl[k + 2][r] = v.z; Wl[k + 3][r] = v.w;
        }
    }
    __syncthreads();

    const int tm = (tid & 15) * 4;
    const int tn = (tid >> 4) * 4;
    float acc[4][4] = {};
    #pragma unroll 8
    for (int k = 0; k < 128; ++k) {
        float4 av = *reinterpret_cast<const float4*>(&Al[k][tm]);
        float4 wv = *reinterpret_cast<const float4*>(&Wl[k][tn]);
        acc[0][0] = fmaf(av.x, wv.x, acc[0][0]);
        acc[0][1] = fmaf(av.x, wv.y, acc[0][1]);
        acc[0][2] = fmaf(av.x, wv.z, acc[0][2]);
        acc[0][3] = fmaf(av.x, wv.w, acc[0][3]);
        acc[1][0] = fmaf(av.y, wv.x, acc[1][0]);
        acc[1][1] = fmaf(av.y, wv.y, acc[1][1]);
        acc[1][2] = fmaf(av.y, wv.z, acc[1][2]);
        acc[1][3] = fmaf(av.y, wv.w, acc[1][3]);
        acc[2][0] = fmaf(av.z, wv.x, acc[2][0]);
        acc[2][1] = fmaf(av.z, wv.y, acc[2][1]);
        acc[2][2] = fmaf(av.z, wv.z, acc[2][2]);
        acc[2][3] = fmaf(av.z, wv.w, acc[2][3]);
        acc[3][0] = fmaf(av.w, wv.x, acc[3][0]);
        acc[3][1] = fmaf(av.w, wv.y, acc[3][1]);
        acc[3][2] = fmaf(av.w, wv.z, acc[3][2]);
        acc[3][3] = fmaf(av.w, wv.w, acc[3][3]);
    }

    float bias[4];
    #pragma unroll
    for (int i = 0; i < 4; ++i) {
        int n = n_base + tn + i;
        bias[i] = b1[n] + (b2 ? b2[n] : 0.0f);
    }
    #pragma unroll
    for (int mi = 0; mi < 4; ++mi) {
        float4 o;
        o.x = acc[mi][0] + bias[0];
        o.y = acc[mi][1] + bias[1];
        o.z = acc[mi][2] + bias[2];
        o.w = acc[mi][3] + bias[3];
        *reinterpret_cast<float4*>(C + (size_t)(m_base + tm + mi) * N + n_base + tn) = o;
    }
}

// ---------------------------------------------------------------------------
__global__ __launch_bounds__(512)
void bn_stats_kernel(const float* __restrict__ Z,       // (T,128)
                     const float* __restrict__ gamma,
                     const float* __restrict__ beta,
                     float* __restrict__ scale,
                     float* __restrict__ shift)
{
    const int tid = threadIdx.x;
    const int col = tid & 127;
    const int seg = tid >> 7;     // 0..3
    float s = 0.f, sq = 0.f;
    for (int t = seg * 512; t < (seg + 1) * 512; ++t) {
        float v = Z[(size_t)t * 128 + col];
        s += v;
        sq = fmaf(v, v, sq);
    }
    __shared__ float ps[4][128], pq[4][128];
    ps[seg][col] = s;
    pq[seg][col] = sq;
    __syncthreads();
    if (tid < 128) {
        float sum = ps[0][tid] + ps[1][tid] + ps[2][tid] + ps[3][tid];
        float sqq = pq[0][tid] + pq[1][tid] + pq[2][tid] + pq[3][tid];
        float mean = sum * (1.0f / 2048.0f);
        float var  = sqq * (1.0f / 2048.0f) - mean * mean;
        float sc = gamma[tid] * rsqrtf(var + 1e-5f);
        scale[tid] = sc;
        shift[tid] = beta[tid] - mean * sc;
    }
}

// ---------------------------------------------------------------------------
__global__ __launch_bounds__(512)
void fc2_kernel(const float* __restrict__ Z,      // (T,128)
                const float* __restrict__ scale,
                const float* __restrict__ shift,
                const float* __restrict__ fc2_w,  // (8,128)
                const float* __restrict__ fc2_b,
                float* __restrict__ out)          // (T,8)
{
    const int gid = blockIdx.x * blockDim.x + threadIdx.x;   // 0..16383
    const int o = gid & 7;
    const int t = gid >> 3;

    __shared__ float w_s[8][132];
    __shared__ float sc_s[128], sh_s[128];
    for (int i = threadIdx.x; i < 1024; i += 512) w_s[i >> 7][i & 127] = fc2_w[i];
    if (threadIdx.x < 128) {
        sc_s[threadIdx.x] = scale[threadIdx.x];
        sh_s[threadIdx.x] = shift[threadIdx.x];
    }
    __syncthreads();

    float acc = fc2_b[o];
    const float* zrow = Z + (size_t)t * 128;
    #pragma unroll 4
    for (int k = 0; k < 128; ++k) {
        float zn = fmaf(zrow[k], sc_s[k], sh_s[k]);
        zn = fmaxf(zn, 0.0f);
        acc = fmaf(zn, w_s[o][k], acc);
    }
    out[gid] = acc;
}

// ---------------------------------------------------------------------------
extern "C" void kernel_launch(void* const* d_in, const int* in_sizes, int n_in,
                              void* d_out, int out_size, void* d_ws, size_t ws_size,
                              hipStream_t stream)
{
    const float* x     = (const float*)d_in[0];   // (2048,128,1)
    const float* Wih0  = (const float*)d_in[1];   // (512,1)
    const float* Whh0  = (const float*)d_in[2];   // (512,128)
    const float* bih0  = (const float*)d_in[3];
    const float* bhh0  = (const float*)d_in[4];
    const float* Wih1  = (const float*)d_in[5];   // (512,128)
    const float* Whh1  = (const float*)d_in[6];   // (512,128)
    const float* bih1  = (const float*)d_in[7];
    const float* bhh1  = (const float*)d_in[8];
    const float* fc1_w = (const float*)d_in[9];   // (128,128)
    const float* fc1_b = (const float*)d_in[10];
    const float* gamma = (const float*)d_in[11];
    const float* beta  = (const float*)d_in[12];
    const float* fc2_w = (const float*)d_in[13];  // (8,128)
    const float* fc2_b = (const float*)d_in[14];
    float* out = (float*)d_out;                    // (2048,8) fp32

    float* h1    = (float*)d_ws;            // 2048*128
    float* G     = h1  + T_STEPS * HID;     // 2048*512
    float* h2    = G   + T_STEPS * G4;      // 2048*128
    float* z     = h2  + T_STEPS * HID;     // 2048*128
    float* scale = z   + T_STEPS * HID;     // 128
    float* shift = scale + 128;             // 128

    // K1: layer-0 recurrence (only batch element 127 matters)
    lstm_rec_mfma<true><<<1, 512, 0, stream>>>(Whh0, x, Wih0, bih0, bhh0, h1);

    // K2: layer-1 input GEMM: G[t,:] = h1[t,:] @ Wih1^T + (bih1+bhh1)
    dim3 g2(T_STEPS / BM, G4 / BN);
    gemm_bias_kernel<<<g2, 256, 0, stream>>>(h1, Wih1, bih1, bhh1, G, T_STEPS, G4);

    // K3: layer-1 recurrence consuming precomputed G
    lstm_rec_mfma<false><<<1, 512, 0, stream>>>(Whh1, G, nullptr, nullptr, nullptr, h2);

    // K4a: z = h2 @ fc1^T + fc1_b
    dim3 g4(T_STEPS / BM, HID / BN);
    gemm_bias_kernel<<<g4, 256, 0, stream>>>(h2, fc1_w, fc1_b, nullptr, z, T_STEPS, HID);

    // K4b: batchnorm stats over T axis
    bn_stats_kernel<<<1, 512, 0, stream>>>(z, gamma, beta, scale, shift);

    // K4c: normalize + relu + fc2
    fc2_kernel<<<T_STEPS * 8 / 512, 512, 0, stream>>>(z, scale, shift, fc2_w, fc2_b, out);
}

// Round 10
// 3502.603 us; speedup vs baseline: 1.8479x; 1.0918x over previous
//
#include <hip/hip_runtime.h>
#include <math.h>

#define T_STEPS 2048
#define HID     128
#define G4      512   // 4*H

typedef _Float16 half8 __attribute__((ext_vector_type(8)));
typedef float    f32x4 __attribute__((ext_vector_type(4)));
typedef int      i32x4 __attribute__((ext_vector_type(4)));

__device__ __forceinline__ float fast_sig(float x) {
    return __fdividef(1.0f, 1.0f + __expf(-x));
}
__device__ __forceinline__ float fast_tanh(float x) {
    return fmaf(2.0f, __fdividef(1.0f, 1.0f + __expf(-2.0f * x)), -1.0f);
}

union HU { half8 h; i32x4 i; };

// f16 A-fragment for (type r, kt): A row = 128r + jb0 + col (tile = 16 units
// of gate-type r), k = kt*32 + quad*8 + j
__device__ __forceinline__ i32x4 make_frag(const float* __restrict__ Whh,
                                           int jb0, int r, int kt,
                                           int col, int quad) {
    const float* p = Whh + (size_t)(r * 128 + jb0 + col) * HID + kt * 32 + quad * 8;
    float4 lo = *reinterpret_cast<const float4*>(p);
    float4 hi = *reinterpret_cast<const float4*>(p + 4);
    HU u;
    u.h[0] = (_Float16)lo.x; u.h[1] = (_Float16)lo.y;
    u.h[2] = (_Float16)lo.z; u.h[3] = (_Float16)lo.w;
    u.h[4] = (_Float16)hi.x; u.h[5] = (_Float16)hi.y;
    u.h[6] = (_Float16)hi.z; u.h[7] = (_Float16)hi.w;
    return u.i;
}

#define PUT(B0,B1,B2,B3,R,KT)                                                  \
    { i32x4 u = make_frag(Whh, jb0, R, KT, col, quad);                         \
      asm volatile("v_accvgpr_write_b32 a" #B0 ", %0\n\t"                      \
                   "v_accvgpr_write_b32 a" #B1 ", %1\n\t"                      \
                   "v_accvgpr_write_b32 a" #B2 ", %2\n\t"                      \
                   "v_accvgpr_write_b32 a" #B3 ", %3"                          \
                   :: "v"(u[0]), "v"(u[1]), "v"(u[2]), "v"(u[3])               \
                   : "a" #B0, "a" #B1, "a" #B2, "a" #B3); }

#define A_CLOBBERS \
    "a0","a1","a2","a3","a4","a5","a6","a7","a8","a9","a10","a11","a12","a13", \
    "a14","a15","a16","a17","a18","a19","a20","a21","a22","a23","a24","a25",   \
    "a26","a27","a28","a29","a30","a31","a32","a33","a34","a35","a36","a37",   \
    "a38","a39","a40","a41","a42","a43","a44","a45","a46","a47","a48","a49",   \
    "a50","a51","a52","a53","a54","a55","a56","a57","a58","a59","a60","a61",   \
    "a62","a63","a64","a65","a66","a67","a68","a69","a70","a71","a72","a73",   \
    "a74","a75","a76","a77","a78","a79","a80","a81","a82","a83"

// ---------------------------------------------------------------------------
// MFMA LSTM recurrence, single live batch element (b = 127).
//
// ROUND-9 FALSIFICATION: with weights fully AGPR-resident (FETCH = weights
// once, no scratch), the step time barely moved (~2580 cyc). The cost is the
// step's SERIAL PHASE STRUCTURE: 2 full __syncthreads (each draining vmcnt
// incl. the hout store ack), 2 LDS round trips (gact), a 2-wave serial tail,
// and the activation/readout VALU chain. This round collapses all of it:
//
// - Row-tiles remapped: chain r = GATE TYPE r (rows 128r+16w..+15). Each
//   lane then holds all 4 gate types of units 16w+4q+{0..3}; a 12-cndmask
//   in-lane select (by col&3) gives ONE unit's (i,f,g,o) per lane -> trans
//   work not replicated, and the c/h update is IN-LANE (c replicated over
//   col>>2, deterministic).
// - gact LDS array, barrier #2, and the serial tail are GONE. Lanes col<4
//   write h16 (ds_write_b16) + hout; ONE barrier per step.
// - Custom barrier `s_waitcnt lgkmcnt(0); s_barrier` -- global-store acks
//   never block the step (the compiler's __syncthreads drains vmcnt(0)).
// - L0's bias/Wih path moved to a G0 pre-pass; both layers consume a
//   precomputed G (T,512): pre[r] = G[t*512 + 128r + unit], 4 dword loads
//   per lane issued at step top, consumed after the MFMA readout.
//
// Weights stay in PHYSICAL AGPRs a0..a63 (round-9 proven: asm
// v_accvgpr_write + a-clobbers; RA cannot spill them). Accums a64..a79,
// zero-quad a80..a83. 2x s_nop 7 before v_accvgpr_read covers the hazard.
// ---------------------------------------------------------------------------
__global__ __launch_bounds__(512)
void lstm_rec_mfma(const float* __restrict__ Whh,   // (512,128) row-major
                   const float* __restrict__ Gpre,  // (T,512) pre-activations
                   float* __restrict__ hout)        // (T,128)
{
    const int tid  = threadIdx.x;
    const int wave = tid >> 6;         // 0..7
    const int lane = tid & 63;
    const int quad = lane >> 4;
    const int col  = lane & 15;
    const int jb0  = wave * 16;        // first hidden unit of this wave
    const int g    = col & 3;          // which of the quad's 4 units this lane owns
    const int unit = jb0 + quad * 4 + g;

    __shared__ __align__(16) _Float16 h16[HID];

    // ---- stage Whh into AGPRs a0..a63: frag (r,kt) -> a[(r*4+kt)*4 ..+3] ----
    PUT( 0, 1, 2, 3, 0, 0)  PUT( 4, 5, 6, 7, 0, 1)
    PUT( 8, 9,10,11, 0, 2)  PUT(12,13,14,15, 0, 3)
    PUT(16,17,18,19, 1, 0)  PUT(20,21,22,23, 1, 1)
    PUT(24,25,26,27, 1, 2)  PUT(28,29,30,31, 1, 3)
    PUT(32,33,34,35, 2, 0)  PUT(36,37,38,39, 2, 1)
    PUT(40,41,42,43, 2, 2)  PUT(44,45,46,47, 2, 3)
    PUT(48,49,50,51, 3, 0)  PUT(52,53,54,55, 3, 1)
    PUT(56,57,58,59, 3, 2)  PUT(60,61,62,63, 3, 3)
    asm volatile("v_accvgpr_write_b32 a80, 0\n\t"
                 "v_accvgpr_write_b32 a81, 0\n\t"
                 "v_accvgpr_write_b32 a82, 0\n\t"
                 "v_accvgpr_write_b32 a83, 0\n\t"
                 "s_nop 7" ::: "a80", "a81", "a82", "a83");

    float c_reg = 0.0f;
    if (tid < HID) h16[tid] = (_Float16)0.0f;
    __syncthreads();

    for (int t = 0; t < T_STEPS; ++t) {
        // pre-activations for THIS lane's unit, all 4 gate types: issue first
        const float* gp = Gpre + (size_t)t * G4 + unit;
        float p_i = gp[0];
        float p_f = gp[128];
        float p_g = gp[256];
        float p_o = gp[384];

        // B fragments: every lane reads the same 8 f16 per k-tile (broadcast)
        i32x4 b0, b1, b2, b3;
        { HU u;
          u.h = *reinterpret_cast<const half8*>(&h16[0 * 32 + quad * 8]); b0 = u.i;
          u.h = *reinterpret_cast<const half8*>(&h16[1 * 32 + quad * 8]); b1 = u.i;
          u.h = *reinterpret_cast<const half8*>(&h16[2 * 32 + quad * 8]); b2 = u.i;
          u.h = *reinterpret_cast<const half8*>(&h16[3 * 32 + quad * 8]); b3 = u.i; }

        // D = Whh @ h : A from resident AGPRs. Chain r = gate type r.
        // acc reg layout: chain r, reg j = gate-type r of unit jb0+4*quad+j.
        float f0, f1, f2, f3, f4, f5, f6, f7, f8, f9, f10, f11, f12, f13, f14, f15;
        asm volatile(
            "v_mfma_f32_16x16x32_f16 a[64:67], a[0:3],   %16, a[80:83]\n\t"
            "v_mfma_f32_16x16x32_f16 a[68:71], a[16:19], %16, a[80:83]\n\t"
            "v_mfma_f32_16x16x32_f16 a[72:75], a[32:35], %16, a[80:83]\n\t"
            "v_mfma_f32_16x16x32_f16 a[76:79], a[48:51], %16, a[80:83]\n\t"
            "v_mfma_f32_16x16x32_f16 a[64:67], a[4:7],   %17, a[64:67]\n\t"
            "v_mfma_f32_16x16x32_f16 a[68:71], a[20:23], %17, a[68:71]\n\t"
            "v_mfma_f32_16x16x32_f16 a[72:75], a[36:39], %17, a[72:75]\n\t"
            "v_mfma_f32_16x16x32_f16 a[76:79], a[52:55], %17, a[76:79]\n\t"
            "v_mfma_f32_16x16x32_f16 a[64:67], a[8:11],  %18, a[64:67]\n\t"
            "v_mfma_f32_16x16x32_f16 a[68:71], a[24:27], %18, a[68:71]\n\t"
            "v_mfma_f32_16x16x32_f16 a[72:75], a[40:43], %18, a[72:75]\n\t"
            "v_mfma_f32_16x16x32_f16 a[76:79], a[56:59], %18, a[76:79]\n\t"
            "v_mfma_f32_16x16x32_f16 a[64:67], a[12:15], %19, a[64:67]\n\t"
            "v_mfma_f32_16x16x32_f16 a[68:71], a[28:31], %19, a[68:71]\n\t"
            "v_mfma_f32_16x16x32_f16 a[72:75], a[44:47], %19, a[72:75]\n\t"
            "v_mfma_f32_16x16x32_f16 a[76:79], a[60:63], %19, a[76:79]\n\t"
            "s_nop 7\n\t"
            "s_nop 7\n\t"
            "v_accvgpr_read_b32 %0,  a64\n\t"
            "v_accvgpr_read_b32 %1,  a65\n\t"
            "v_accvgpr_read_b32 %2,  a66\n\t"
            "v_accvgpr_read_b32 %3,  a67\n\t"
            "v_accvgpr_read_b32 %4,  a68\n\t"
            "v_accvgpr_read_b32 %5,  a69\n\t"
            "v_accvgpr_read_b32 %6,  a70\n\t"
            "v_accvgpr_read_b32 %7,  a71\n\t"
            "v_accvgpr_read_b32 %8,  a72\n\t"
            "v_accvgpr_read_b32 %9,  a73\n\t"
            "v_accvgpr_read_b32 %10, a74\n\t"
            "v_accvgpr_read_b32 %11, a75\n\t"
            "v_accvgpr_read_b32 %12, a76\n\t"
            "v_accvgpr_read_b32 %13, a77\n\t"
            "v_accvgpr_read_b32 %14, a78\n\t"
            "v_accvgpr_read_b32 %15, a79"
            : "=v"(f0), "=v"(f1), "=v"(f2), "=v"(f3),
              "=v"(f4), "=v"(f5), "=v"(f6), "=v"(f7),
              "=v"(f8), "=v"(f9), "=v"(f10), "=v"(f11),
              "=v"(f12), "=v"(f13), "=v"(f14), "=v"(f15)
            : "v"(b0), "v"(b1), "v"(b2), "v"(b3)
            : A_CLOBBERS);

        // in-lane select of this lane's unit (reg index g) per gate type
        float di = (g == 0) ? f0  : (g == 1) ? f1  : (g == 2) ? f2  : f3;
        float df = (g == 0) ? f4  : (g == 1) ? f5  : (g == 2) ? f6  : f7;
        float dg = (g == 0) ? f8  : (g == 1) ? f9  : (g == 2) ? f10 : f11;
        float dodo = (g == 0) ? f12 : (g == 1) ? f13 : (g == 2) ? f14 : f15;

        // activations + c/h update, fully in-lane (replicated over col>>2)
        float ai = fast_sig(di + p_i);
        float af = fast_sig(df + p_f);
        float ag = fast_tanh(dg + p_g);
        float ao = fast_sig(dodo + p_o);
        c_reg = fmaf(af, c_reg, ai * ag);
        float h = ao * fast_tanh(c_reg);

        // writers: one lane per unit (col<4). f16 state + fp32 trajectory.
        if (col < 4) {
            h16[unit] = (_Float16)h;
            hout[(size_t)t * HID + unit] = h;
        }
        // LDS-only barrier: does NOT drain the hout store (vmcnt untouched)
        asm volatile("s_waitcnt lgkmcnt(0)\n\ts_barrier" ::: "memory");
    }
}

// ---------------------------------------------------------------------------
// G0 pre-pass for layer 0: G0[t,j] = x[t,127]*wih0[j] + bih[j]+bhh[j]
// ---------------------------------------------------------------------------
__global__ __launch_bounds__(512)
void g0_kernel(const float* __restrict__ x,      // (T,128)
               const float* __restrict__ wih0,   // (512,)
               const float* __restrict__ bih,
               const float* __restrict__ bhh,
               float* __restrict__ G)            // (T,512)
{
    const int t = blockIdx.x;
    const int j = threadIdx.x;
    G[(size_t)t * G4 + j] = fmaf(x[(size_t)t * HID + HID - 1], wih0[j],
                                 bih[j] + bhh[j]);
}

// ---------------------------------------------------------------------------
// C[m,n] = sum_k A[m,k] * W[n,k] + b1[n] (+ b2[n])    K = 128 fixed
// ---------------------------------------------------------------------------
#define BM 64
#define BN 64
__global__ __launch_bounds__(256)
void gemm_bias_kernel(const float* __restrict__ A,   // (M,128)
                      const float* __restrict__ W,   // (N,128)
                      const float* __restrict__ b1,
                      const float* __restrict__ b2,  // may be null
                      float* __restrict__ C,         // (M,N)
                      int M, int N)
{
    __shared__ float Al[128][BM + 4];
    __shared__ float Wl[128][BN + 4];
    const int tid    = threadIdx.x;
    const int m_base = blockIdx.x * BM;
    const int n_base = blockIdx.y * BN;

    {
        const int r  = tid >> 2;          // 0..63
        const int kq = (tid & 3) * 32;    // 0,32,64,96
        const float4* srcA = reinterpret_cast<const float4*>(A + (size_t)(m_base + r) * 128 + kq);
        #pragma unroll
        for (int i = 0; i < 8; ++i) {
            float4 v = srcA[i];
            int k = kq + 4 * i;
            Al[k + 0][r] = v.x; Al[k + 1][r] = v.y; Al[k + 2][r] = v.z; Al[k + 3][r] = v.w;
        }
        const float4* srcW = reinterpret_cast<const float4*>(W + (size_t)(n_base + r) * 128 + kq);
        #pragma unroll
        for (int i = 0; i < 8; ++i) {
            float4 v = srcW[i];
            int k = kq + 4 * i;
            Wl[k + 0][r] = v.x; Wl[k + 1][r] = v.y; Wl[k + 2][r] = v.z; Wl[k + 3][r] = v.w;
        }
    }
    __syncthreads();

    const int tm = (tid & 15) * 4;
    const int tn = (tid >> 4) * 4;
    float acc[4][4] = {};
    #pragma unroll 8
    for (int k = 0; k < 128; ++k) {
        float4 av = *reinterpret_cast<const float4*>(&Al[k][tm]);
        float4 wv = *reinterpret_cast<const float4*>(&Wl[k][tn]);
        acc[0][0] = fmaf(av.x, wv.x, acc[0][0]);
        acc[0][1] = fmaf(av.x, wv.y, acc[0][1]);
        acc[0][2] = fmaf(av.x, wv.z, acc[0][2]);
        acc[0][3] = fmaf(av.x, wv.w, acc[0][3]);
        acc[1][0] = fmaf(av.y, wv.x, acc[1][0]);
        acc[1][1] = fmaf(av.y, wv.y, acc[1][1]);
        acc[1][2] = fmaf(av.y, wv.z, acc[1][2]);
        acc[1][3] = fmaf(av.y, wv.w, acc[1][3]);
        acc[2][0] = fmaf(av.z, wv.x, acc[2][0]);
        acc[2][1] = fmaf(av.z, wv.y, acc[2][1]);
        acc[2][2] = fmaf(av.z, wv.z, acc[2][2]);
        acc[2][3] = fmaf(av.z, wv.w, acc[2][3]);
        acc[3][0] = fmaf(av.w, wv.x, acc[3][0]);
        acc[3][1] = fmaf(av.w, wv.y, acc[3][1]);
        acc[3][2] = fmaf(av.w, wv.z, acc[3][2]);
        acc[3][3] = fmaf(av.w, wv.w, acc[3][3]);
    }

    float bias[4];
    #pragma unroll
    for (int i = 0; i < 4; ++i) {
        int n = n_base + tn + i;
        bias[i] = b1[n] + (b2 ? b2[n] : 0.0f);
    }
    #pragma unroll
    for (int mi = 0; mi < 4; ++mi) {
        float4 o;
        o.x = acc[mi][0] + bias[0];
        o.y = acc[mi][1] + bias[1];
        o.z = acc[mi][2] + bias[2];
        o.w = acc[mi][3] + bias[3];
        *reinterpret_cast<float4*>(C + (size_t)(m_base + tm + mi) * N + n_base + tn) = o;
    }
}

// ---------------------------------------------------------------------------
__global__ __launch_bounds__(512)
void bn_stats_kernel(const float* __restrict__ Z,       // (T,128)
                     const float* __restrict__ gamma,
                     const float* __restrict__ beta,
                     float* __restrict__ scale,
                     float* __restrict__ shift)
{
    const int tid = threadIdx.x;
    const int col = tid & 127;
    const int seg = tid >> 7;     // 0..3
    float s = 0.f, sq = 0.f;
    for (int t = seg * 512; t < (seg + 1) * 512; ++t) {
        float v = Z[(size_t)t * 128 + col];
        s += v;
        sq = fmaf(v, v, sq);
    }
    __shared__ float ps[4][128], pq[4][128];
    ps[seg][col] = s;
    pq[seg][col] = sq;
    __syncthreads();
    if (tid < 128) {
        float sum = ps[0][tid] + ps[1][tid] + ps[2][tid] + ps[3][tid];
        float sqq = pq[0][tid] + pq[1][tid] + pq[2][tid] + pq[3][tid];
        float mean = sum * (1.0f / 2048.0f);
        float var  = sqq * (1.0f / 2048.0f) - mean * mean;
        float sc = gamma[tid] * rsqrtf(var + 1e-5f);
        scale[tid] = sc;
        shift[tid] = beta[tid] - mean * sc;
    }
}

// ---------------------------------------------------------------------------
__global__ __launch_bounds__(512)
void fc2_kernel(const float* __restrict__ Z,      // (T,128)
                const float* __restrict__ scale,
                const float* __restrict__ shift,
                const float* __restrict__ fc2_w,  // (8,128)
                const float* __restrict__ fc2_b,
                float* __restrict__ out)          // (T,8)
{
    const int gid = blockIdx.x * blockDim.x + threadIdx.x;   // 0..16383
    const int o = gid & 7;
    const int t = gid >> 3;

    __shared__ float w_s[8][132];
    __shared__ float sc_s[128], sh_s[128];
    for (int i = threadIdx.x; i < 1024; i += 512) w_s[i >> 7][i & 127] = fc2_w[i];
    if (threadIdx.x < 128) {
        sc_s[threadIdx.x] = scale[threadIdx.x];
        sh_s[threadIdx.x] = shift[threadIdx.x];
    }
    __syncthreads();

    float acc = fc2_b[o];
    const float* zrow = Z + (size_t)t * 128;
    #pragma unroll 4
    for (int k = 0; k < 128; ++k) {
        float zn = fmaf(zrow[k], sc_s[k], sh_s[k]);
        zn = fmaxf(zn, 0.0f);
        acc = fmaf(zn, w_s[o][k], acc);
    }
    out[gid] = acc;
}

// ---------------------------------------------------------------------------
extern "C" void kernel_launch(void* const* d_in, const int* in_sizes, int n_in,
                              void* d_out, int out_size, void* d_ws, size_t ws_size,
                              hipStream_t stream)
{
    const float* x     = (const float*)d_in[0];   // (2048,128,1)
    const float* Wih0  = (const float*)d_in[1];   // (512,1)
    const float* Whh0  = (const float*)d_in[2];   // (512,128)
    const float* bih0  = (const float*)d_in[3];
    const float* bhh0  = (const float*)d_in[4];
    const float* Wih1  = (const float*)d_in[5];   // (512,128)
    const float* Whh1  = (const float*)d_in[6];   // (512,128)
    const float* bih1  = (const float*)d_in[7];
    const float* bhh1  = (const float*)d_in[8];
    const float* fc1_w = (const float*)d_in[9];   // (128,128)
    const float* fc1_b = (const float*)d_in[10];
    const float* gamma = (const float*)d_in[11];
    const float* beta  = (const float*)d_in[12];
    const float* fc2_w = (const float*)d_in[13];  // (8,128)
    const float* fc2_b = (const float*)d_in[14];
    float* out = (float*)d_out;                    // (2048,8) fp32

    // workspace: G shared between layers (L0 consumes before K2 overwrites)
    float* G     = (float*)d_ws;            // 2048*512
    float* h1    = G   + T_STEPS * G4;      // 2048*128
    float* h2    = h1  + T_STEPS * HID;     // 2048*128
    float* z     = h2  + T_STEPS * HID;     // 2048*128
    float* scale = z   + T_STEPS * HID;     // 128
    float* shift = scale + 128;             // 128

    // K0: layer-0 pre-activation pre-pass
    g0_kernel<<<T_STEPS, 512, 0, stream>>>(x, Wih0, bih0, bhh0, G);

    // K1: layer-0 recurrence
    lstm_rec_mfma<<<1, 512, 0, stream>>>(Whh0, G, h1);

    // K2: layer-1 input GEMM: G[t,:] = h1[t,:] @ Wih1^T + (bih1+bhh1)
    dim3 g2(T_STEPS / BM, G4 / BN);
    gemm_bias_kernel<<<g2, 256, 0, stream>>>(h1, Wih1, bih1, bhh1, G, T_STEPS, G4);

    // K3: layer-1 recurrence
    lstm_rec_mfma<<<1, 512, 0, stream>>>(Whh1, G, h2);

    // K4a: z = h2 @ fc1^T + fc1_b
    dim3 g4(T_STEPS / BM, HID / BN);
    gemm_bias_kernel<<<g4, 256, 0, stream>>>(h2, fc1_w, fc1_b, nullptr, z, T_STEPS, HID);

    // K4b: batchnorm stats over T axis
    bn_stats_kernel<<<1, 512, 0, stream>>>(z, gamma, beta, scale, shift);

    // K4c: normalize + relu + fc2
    fc2_kernel<<<T_STEPS * 8 / 512, 512, 0, stream>>>(z, scale, shift, fc2_w, fc2_b, out);
}